// Round 14
// baseline (50.482 us; speedup 1.0000x reference)
//
#include <hip/hip_runtime.h>
#include <hip/hip_bf16.h>

// Problem constants
#define BATCH   8192
#define NGRP    8
#define MAXGS   64
#define DMODEL  2048
#define TM      16
#define TILES   (BATCH / TM)      // 512
#define NBLK    32                // bucket blocks (256 thr each)

typedef __attribute__((ext_vector_type(8))) short  short8;
typedef __attribute__((ext_vector_type(4))) float  f32x4;

// ws layout
#define CNT_OFF   0                        // int cnt[8*16] (64B-padded)
#define HIST_OFF  512                      // int hist[32][8]
#define BASES_OFF 1536                     // int bases[32][8]
#define LISTS_OFF 4096                     // int lists[8][8192]
#define W_OFF     (LISTS_OFF + NGRP * BATCH * 4)
#define CNT_STRIDE 16
#define NKK     (DMODEL / 32)     // 64 K-chunks

static __device__ __forceinline__ short bf(float f) {
    __hip_bfloat16 h = __float2bfloat16(f);
    return (short)__bfloat16_as_ushort(h);
}

// Phase 0 (fused): blocks < 1024 repack W (f32 [g][c][k] -> bf16 Wb2
// [g][kk][c][j], 1KB-contiguous per-MFMA B); blocks >= 1024 compute the
// per-block group histogram of `chosen` (LDS counts, no global atomics).
__global__ __launch_bounds__(256) void init_hist_kernel(
    const float* __restrict__ W,
    const int* __restrict__ chosen,
    unsigned short* __restrict__ Wb2,
    int* __restrict__ hist)
{
    int blk = blockIdx.x;
    int tid = threadIdx.x;
    if (blk < 1024) {
        int e = (blk * 256 + tid) * 4;
        int g = e >> 17;
        int rem = e & ((MAXGS * DMODEL) - 1);
        int c = rem >> 11;
        int k = rem & (DMODEL - 1);
        int kk = k >> 5, j = k & 31;
        float4 w = *reinterpret_cast<const float4*>(W + e);
        ushort4 o;
        o.x = (unsigned short)bf(w.x); o.y = (unsigned short)bf(w.y);
        o.z = (unsigned short)bf(w.z); o.w = (unsigned short)bf(w.w);
        size_t dst = (((size_t)g * NKK + kk) * MAXGS + c) * 32 + j;
        *reinterpret_cast<ushort4*>(Wb2 + dst) = o;
    } else {
        int hb = blk - 1024;               // 0..31
        __shared__ int h[NGRP];
        if (tid < NGRP) h[tid] = 0;
        __syncthreads();
        int g = chosen[hb * 256 + tid];
        atomicAdd(&h[g], 1);               // LDS atomic
        __syncthreads();
        if (tid < NGRP) hist[hb * NGRP + tid] = h[tid];
    }
}

// Phase 1: scan 32 block-histograms per group -> exclusive bases + totals.
// 1 block, 8 active threads, 32 serial adds each: trivial.
__global__ __launch_bounds__(64) void scan_kernel(const int* __restrict__ hist,
                                                  int* __restrict__ bases,
                                                  int* __restrict__ cnt) {
    int tid = threadIdx.x;
    if (tid < NGRP) {
        int s = 0;
        for (int blk = 0; blk < NBLK; ++blk) {
            bases[blk * NGRP + tid] = s;
            s += hist[blk * NGRP + tid];
        }
        cnt[tid * CNT_STRIDE] = s;
    }
}

// Phase 2: scatter in ASCENDING-b order (deterministic, no global atomics).
// pos = group_base_of_block + wave-exclusive-scan + ballot-prefix rank.
// WHY SORTED: old atomic bucket produced a random permutation -> chip-wide
// random 256B bursts per HBM channel -> row-activate per burst -> 1.36 TB/s
// measured HBM rate during gemm (r6 probe), the invariant wall of ALL nine
// structures. Ascending rows restore sequential-activation streaming.
__global__ __launch_bounds__(256) void scatter_kernel(const int* __restrict__ chosen,
                                                      const int* __restrict__ bases,
                                                      int* __restrict__ lists) {
    __shared__ int wcnt[4][NGRP];
    __shared__ int wbase[4][NGRP];
    int tid  = threadIdx.x;
    int blk  = blockIdx.x;
    int w    = tid >> 6;
    int lane = tid & 63;
    int b = blk * 256 + tid;
    int g = chosen[b];

    int rank = 0;
    unsigned long long below = (lane == 63) ? ~0ull >> 1 << 0 : ((1ull << lane) - 1ull);
    below = (1ull << lane) - 1ull;          // lanes strictly below me
    #pragma unroll
    for (int gg = 0; gg < NGRP; ++gg) {
        unsigned long long m = __ballot(g == gg);
        if (g == gg) rank = __popcll(m & below);
        if (lane == gg) wcnt[w][gg] = __popcll(m);   // lane gg records count
    }
    __syncthreads();
    if (tid < NGRP) {                       // scan 4 waves for group tid
        int base = bases[blk * NGRP + tid];
        #pragma unroll
        for (int ww = 0; ww < 4; ++ww) {
            wbase[ww][tid] = base;
            base += wcnt[ww][tid];
        }
    }
    __syncthreads();
    lists[g * BATCH + wbase[w][g] + rank] = b;   // order = ascending b
}

// Phase 3: LDS-free per-wave GEMM (r13 unchanged; only list ORDER differs).
// One 64-thread wave owns a 16-sample x 64-col tile; A in registers,
// prefetched 3 chunks ahead; B from coalesced Wb2 (1KB contiguous per MFMA).
// MFMA C/D: col = lane&15 (within col-group), row = (lane>>4)*4 + reg.
__global__ __launch_bounds__(64, 2) void gemm_kernel(
    const float* __restrict__ hidden,
    const float* __restrict__ bias,
    const int* __restrict__ gsizes,
    const int* __restrict__ cnt,
    const int* __restrict__ lists,
    const unsigned short* __restrict__ Wb2,
    float* __restrict__ out)
{
    int bid = blockIdx.x;
    int g = bid & (NGRP - 1);
    int t = bid >> 3;
    int c = cnt[g * CNT_STRIDE];
    int m0 = t * TM;
    if (m0 >= c) return;

    int lane = threadIdx.x;
    int lrow = lane & 15;
    int kg   = lane >> 4;

    int mrow  = m0 + lrow;
    int msafe = mrow < c ? mrow : c - 1;
    int smp   = lists[g * BATCH + msafe];

    const float* __restrict__ ap =
        hidden + ((size_t)smp * NGRP + g) * DMODEL + kg * 8;
    const unsigned short* __restrict__ bp =
        Wb2 + (size_t)g * NKK * MAXGS * 32 + lrow * 32 + kg * 8;

    f32x4 ra[4][8];
    f32x4 acc[4] = {f32x4{0,0,0,0}, f32x4{0,0,0,0}, f32x4{0,0,0,0}, f32x4{0,0,0,0}};

    #pragma unroll
    for (int pc = 0; pc < 3; ++pc)
        #pragma unroll
        for (int j = 0; j < 4; ++j) {
            ra[pc][2*j]   = *reinterpret_cast<const f32x4*>(ap + (pc*4 + j)*32);
            ra[pc][2*j+1] = *reinterpret_cast<const f32x4*>(ap + (pc*4 + j)*32 + 4);
        }

    #pragma unroll
    for (int ch = 0; ch < 16; ++ch) {
        if (ch + 3 < 16) {
            #pragma unroll
            for (int j = 0; j < 4; ++j) {
                ra[(ch+3) & 3][2*j]   =
                    *reinterpret_cast<const f32x4*>(ap + ((ch+3)*4 + j)*32);
                ra[(ch+3) & 3][2*j+1] =
                    *reinterpret_cast<const f32x4*>(ap + ((ch+3)*4 + j)*32 + 4);
            }
        }
        #pragma unroll
        for (int j = 0; j < 4; ++j) {
            f32x4 alo = ra[ch & 3][2*j];
            f32x4 ahi = ra[ch & 3][2*j+1];
            short8 af;
            af[0] = bf(alo[0]); af[1] = bf(alo[1]); af[2] = bf(alo[2]); af[3] = bf(alo[3]);
            af[4] = bf(ahi[0]); af[5] = bf(ahi[1]); af[6] = bf(ahi[2]); af[7] = bf(ahi[3]);
            int kk = ch*4 + j;
            #pragma unroll
            for (int cg = 0; cg < 4; ++cg) {
                short8 bfr = *reinterpret_cast<const short8*>(
                    bp + ((size_t)kk * MAXGS + cg * 16) * 32);
                acc[cg] = __builtin_amdgcn_mfma_f32_16x16x32_bf16(af, bfr, acc[cg], 0, 0, 0);
            }
        }
    }

    int gsz = gsizes[g];
    #pragma unroll
    for (int r = 0; r < 4; ++r) {
        int m = m0 + kg * 4 + r;
        if (m < c) {
            int s = lists[g * BATCH + m];
            float* prow = out + (size_t)s * MAXGS;
            float* vrow = out + (size_t)(BATCH + s) * MAXGS;
            #pragma unroll
            for (int cg = 0; cg < 4; ++cg) {
                int n = cg * 16 + lrow;
                prow[n] = acc[cg][r] + bias[g * MAXGS + n];
                vrow[n] = (n < gsz) ? 1.0f : 0.0f;
            }
        }
    }
}

extern "C" void kernel_launch(void* const* d_in, const int* in_sizes, int n_in,
                              void* d_out, int out_size, void* d_ws, size_t ws_size,
                              hipStream_t stream) {
    const float* hidden = (const float*)d_in[0];   // [8192, 8, 2048] f32
    const int*   chosen = (const int*)d_in[1];     // [8192] i32
    const float* W      = (const float*)d_in[2];   // [8, 64, 2048] f32 (zero-padded)
    const float* bias   = (const float*)d_in[3];   // [8, 64] f32 (zero-padded)
    const int*   gs     = (const int*)d_in[4];     // [8] i32
    float* out = (float*)d_out;                    // [8192*64 preds | 8192*64 valid]

    char* ws = (char*)d_ws;
    int* cnt   = (int*)(ws + CNT_OFF);
    int* hist  = (int*)(ws + HIST_OFF);
    int* bases = (int*)(ws + BASES_OFF);
    int* lists = (int*)(ws + LISTS_OFF);
    unsigned short* Wb2 = (unsigned short*)(ws + W_OFF);

    init_hist_kernel<<<dim3(1024 + NBLK), dim3(256), 0, stream>>>(W, chosen, Wb2, hist);
    scan_kernel<<<dim3(1), dim3(64), 0, stream>>>(hist, bases, cnt);
    scatter_kernel<<<dim3(NBLK), dim3(256), 0, stream>>>(chosen, bases, lists);
    gemm_kernel<<<dim3(NGRP * TILES), dim3(64), 0, stream>>>(
        hidden, bias, gs, cnt, lists, Wb2, out);
}

// Round 15
// 38.163 us; speedup vs baseline: 1.3228x; 1.3228x over previous
//
#include <hip/hip_runtime.h>
#include <hip/hip_bf16.h>

// Problem constants
#define BATCH   8192
#define NGRP    8
#define MAXGS   64
#define DMODEL  2048
#define TM      16
#define TILES   (BATCH / TM)      // 512
#define NBLK    32                // histogram/scatter blocks
#define NKK     (DMODEL / 32)     // 64 K-chunks

typedef __attribute__((ext_vector_type(8))) short  short8;
typedef __attribute__((ext_vector_type(4))) float  f32x4;
typedef __attribute__((ext_vector_type(4))) short  short4v;

// ws layout
#define CNT_OFF   0                        // int cnt[8*16] (64B-padded)
#define HIST_OFF  512                      // int hist[32][8]
#define BASES_OFF 1536                     // int bases[32][8]
#define LISTS_OFF 4096                     // int lists[8][8192]
#define W_OFF     (LISTS_OFF + NGRP * BATCH * 4)
#define CNT_STRIDE 16

static __device__ __forceinline__ short bf(float f) {
    __hip_bfloat16 h = __float2bfloat16(f);
    return (short)__bfloat16_as_ushort(h);
}

// Phase 0 (fused): blocks < 1024 repack W (f32 [g][c][k] -> bf16 Wb2
// [g][kk][c][j], k = kk*32+j): per-MFMA B-load becomes 1KB CONTIGUOUS
// (fixes the 4KB-row-stride L2 channel pileup = the 22us compute wall,
// probe_c r11). Blocks >= 1024: per-block group histogram of `chosen`.
__global__ __launch_bounds__(256) void init_hist_kernel(
    const float* __restrict__ W,
    const int* __restrict__ chosen,
    unsigned short* __restrict__ Wb2,
    int* __restrict__ hist)
{
    int blk = blockIdx.x;
    int tid = threadIdx.x;
    if (blk < 1024) {
        int e = (blk * 256 + tid) * 4;
        int g = e >> 17;
        int rem = e & ((MAXGS * DMODEL) - 1);
        int c = rem >> 11;
        int k = rem & (DMODEL - 1);
        int kk = k >> 5, j = k & 31;
        float4 w = *reinterpret_cast<const float4*>(W + e);
        ushort4 o;
        o.x = (unsigned short)bf(w.x); o.y = (unsigned short)bf(w.y);
        o.z = (unsigned short)bf(w.z); o.w = (unsigned short)bf(w.w);
        size_t dst = (((size_t)g * NKK + kk) * MAXGS + c) * 32 + j;
        *reinterpret_cast<ushort4*>(Wb2 + dst) = o;
    } else {
        int hb = blk - 1024;               // 0..31
        __shared__ int h[NGRP];
        if (tid < NGRP) h[tid] = 0;
        __syncthreads();
        int g = chosen[hb * 256 + tid];
        atomicAdd(&h[g], 1);               // LDS atomic
        __syncthreads();
        if (tid < NGRP) hist[hb * NGRP + tid] = h[tid];
    }
}

// Phase 1: scan 32 block-histograms per group -> exclusive bases + totals.
__global__ __launch_bounds__(64) void scan_kernel(const int* __restrict__ hist,
                                                  int* __restrict__ bases,
                                                  int* __restrict__ cnt) {
    int tid = threadIdx.x;
    if (tid < NGRP) {
        int s = 0;
        for (int blk = 0; blk < NBLK; ++blk) {
            bases[blk * NGRP + tid] = s;
            s += hist[blk * NGRP + tid];
        }
        cnt[tid * CNT_STRIDE] = s;
    }
}

// Phase 2: deterministic ascending-b scatter (ballot-prefix ranks).
__global__ __launch_bounds__(256) void scatter_kernel(const int* __restrict__ chosen,
                                                      const int* __restrict__ bases,
                                                      int* __restrict__ lists) {
    __shared__ int wcnt[4][NGRP];
    __shared__ int wbase[4][NGRP];
    int tid  = threadIdx.x;
    int blk  = blockIdx.x;
    int w    = tid >> 6;
    int lane = tid & 63;
    int b = blk * 256 + tid;
    int g = chosen[b];

    int rank = 0;
    unsigned long long below = (1ull << lane) - 1ull;
    #pragma unroll
    for (int gg = 0; gg < NGRP; ++gg) {
        unsigned long long m = __ballot(g == gg);
        if (g == gg) rank = __popcll(m & below);
        if (lane == gg) wcnt[w][gg] = __popcll(m);
    }
    __syncthreads();
    if (tid < NGRP) {
        int base = bases[blk * NGRP + tid];
        #pragma unroll
        for (int ww = 0; ww < 4; ++ww) {
            wbase[ww][tid] = base;
            base += wcnt[ww][tid];
        }
    }
    __syncthreads();
    lists[g * BATCH + wbase[w][g] + rank] = b;
}

// Phase 3: GEMM = r10's burst staging (Wall A fix: each 8KB A-row read as
// 8 back-to-back 1KB loads -> DRAM pages consumed whole, measured ~5.8 TB/s)
// + r13's coalesced B (Wall B fix: 1KB contiguous per wave B-load, L2-clean).
// Every previous design fixed exactly ONE wall (r10: A, badB=22us; r12/13:
// B, badA~26us) -- which is why ten structures all landed at 31-35us.
// A staged bf16 in LDS, swizzle byte^=((r&7)<<4)|((r&1)<<6) (r11-measured
// conflicts negligible). One barrier. Waves n-split 16 cols, full K.
// MFMA C/D: col = lane&15, row = (lane>>4)*4 + reg.
__global__ __launch_bounds__(256, 2) void gemm_kernel(
    const float* __restrict__ hidden,
    const float* __restrict__ bias,
    const int* __restrict__ gsizes,
    const int* __restrict__ cnt,
    const int* __restrict__ lists,
    const unsigned short* __restrict__ Wb2,
    float* __restrict__ out)
{
    int bid = blockIdx.x;
    int g = bid & (NGRP - 1);      // group <-> XCD alignment: Wb2[g] L2-resident
    int t = bid >> 3;
    int c = cnt[g * CNT_STRIDE];
    int m0 = t * TM;
    if (m0 >= c) return;           // uniform dead-block exit

    __shared__ unsigned short A[TM][DMODEL];   // bf16, 64 KB

    int tid  = threadIdx.x;
    int w    = tid >> 6;           // wave 0..3
    int lane = tid & 63;
    int lrow = lane & 15;
    int kg   = lane >> 4;          // 0..3

    // ---- stage: wave w owns rows 4w..4w+3; each row = one 8KB burst ----
    {
        const float* src[4];
        #pragma unroll
        for (int i = 0; i < 4; ++i) {
            int m  = m0 + 4 * w + i;
            int ms = m < c ? m : c - 1;          // tail: dup last row (guarded)
            src[i] = hidden + ((size_t)lists[g * BATCH + ms] * NGRP + g) * DMODEL
                   + lane * 4;
        }
        // 2-row software pipeline: 16KB/wave in flight, bursts back-to-back
        f32x4 ra[8], rb[8];
        #pragma unroll
        for (int h = 0; h < 8; ++h)
            ra[h] = *reinterpret_cast<const f32x4*>(src[0] + h * 256);
        #pragma unroll
        for (int h = 0; h < 8; ++h)
            rb[h] = *reinterpret_cast<const f32x4*>(src[1] + h * 256);

        #pragma unroll
        for (int i = 0; i < 4; ++i) {
            int r = 4 * w + i;
            int swz = ((r & 7) << 4) | ((r & 1) << 6);
            char* abase = (char*)&A[r][0];
            #pragma unroll
            for (int h = 0; h < 8; ++h) {
                f32x4 v = ra[h];
                short4v o;
                o[0] = bf(v[0]); o[1] = bf(v[1]); o[2] = bf(v[2]); o[3] = bf(v[3]);
                int byte = (h * 512 + lane * 8) ^ swz;
                *reinterpret_cast<short4v*>(abase + byte) = o;
            }
            if (i < 3) {
                #pragma unroll
                for (int h = 0; h < 8; ++h) ra[h] = rb[h];
                if (i < 2) {
                    #pragma unroll
                    for (int h = 0; h < 8; ++h)
                        rb[h] = *reinterpret_cast<const f32x4*>(src[i + 2] + h * 256);
                }
            }
        }
    }
    __syncthreads();

    // ---- compute: wave w owns cols [16w,16w+16), full K from LDS A ----
    {
        int swzr = ((lrow & 7) << 4) | ((lrow & 1) << 6);
        const char* arow = (const char*)&A[lrow][0];
        // Coalesced B: lane (lrow,kg) reads Wb2[g][kk][w*16+lrow][kg*8..+8)
        // -> wave covers 1KB contiguous inside each kk-slab.
        const unsigned short* bp =
            Wb2 + (size_t)g * NKK * MAXGS * 32 + (w * 16 + lrow) * 32 + kg * 8;

        f32x4 acc = f32x4{0, 0, 0, 0};
        #pragma unroll 8
        for (int kk = 0; kk < NKK; ++kk) {
            int byte = (kk * 64 + kg * 16) ^ swzr;
            short8 af  = *reinterpret_cast<const short8*>(arow + byte);
            short8 bfr = *reinterpret_cast<const short8*>(bp + (size_t)kk * MAXGS * 32);
            acc = __builtin_amdgcn_mfma_f32_16x16x32_bf16(af, bfr, acc, 0, 0, 0);
        }

        // epilogue: C col = lrow (n within group), row = kg*4 + r
        int gsz = gsizes[g];
        int n = w * 16 + lrow;
        float bv = bias[g * MAXGS + n];
        #pragma unroll
        for (int r = 0; r < 4; ++r) {
            int m = m0 + kg * 4 + r;
            if (m < c) {
                int s = lists[g * BATCH + m];
                out[(size_t)s * MAXGS + n] = acc[r] + bv;   // padded n: 0+0 == 0
                out[(size_t)(BATCH + s) * MAXGS + n] = (n < gsz) ? 1.0f : 0.0f;
            }
        }
    }
}

extern "C" void kernel_launch(void* const* d_in, const int* in_sizes, int n_in,
                              void* d_out, int out_size, void* d_ws, size_t ws_size,
                              hipStream_t stream) {
    const float* hidden = (const float*)d_in[0];   // [8192, 8, 2048] f32
    const int*   chosen = (const int*)d_in[1];     // [8192] i32
    const float* W      = (const float*)d_in[2];   // [8, 64, 2048] f32 (zero-padded)
    const float* bias   = (const float*)d_in[3];   // [8, 64] f32 (zero-padded)
    const int*   gs     = (const int*)d_in[4];     // [8] i32
    float* out = (float*)d_out;                    // [8192*64 preds | 8192*64 valid]

    char* ws = (char*)d_ws;
    int* cnt   = (int*)(ws + CNT_OFF);
    int* hist  = (int*)(ws + HIST_OFF);
    int* bases = (int*)(ws + BASES_OFF);
    int* lists = (int*)(ws + LISTS_OFF);
    unsigned short* Wb2 = (unsigned short*)(ws + W_OFF);

    init_hist_kernel<<<dim3(1024 + NBLK), dim3(256), 0, stream>>>(W, chosen, Wb2, hist);
    scan_kernel<<<dim3(1), dim3(64), 0, stream>>>(hist, bases, cnt);
    scatter_kernel<<<dim3(NBLK), dim3(256), 0, stream>>>(chosen, bases, lists);
    gemm_kernel<<<dim3(NGRP * TILES), dim3(256), 0, stream>>>(
        hidden, bias, gs, cnt, lists, Wb2, out);
}

// Round 16
// 36.176 us; speedup vs baseline: 1.3954x; 1.0549x over previous
//
#include <hip/hip_runtime.h>
#include <hip/hip_bf16.h>

// Problem constants
#define BATCH   8192
#define NGRP    8
#define MAXGS   64
#define DMODEL  2048
#define TM      16
#define TILES   (BATCH / TM)      // 512
#define NBLK    32                // histogram/scatter blocks
#define NKK     (DMODEL / 32)     // 64 K-chunks

typedef __attribute__((ext_vector_type(8))) short  short8;
typedef __attribute__((ext_vector_type(4))) float  f32x4;
typedef __attribute__((ext_vector_type(4))) short  short4v;

// ws layout
#define CNT_OFF   0                        // int cnt[8*16] (64B-padded)
#define HIST_OFF  512                      // int hist[32][8]
#define LISTS_OFF 4096                     // int lists[8][8192]
#define W_OFF     (LISTS_OFF + NGRP * BATCH * 4)
#define CNT_STRIDE 16

static __device__ __forceinline__ short bf(float f) {
    __hip_bfloat16 h = __float2bfloat16(f);
    return (short)__bfloat16_as_ushort(h);
}

// Phase 0 (fused): blocks < 1024 repack W (f32 [g][c][k] -> bf16 Wb2
// [g][kk][c][j]): per-MFMA B-load = 1KB contiguous (Wall-B fix, r15-proven).
// Blocks >= 1024: per-block group histogram of `chosen` (LDS atomics).
__global__ __launch_bounds__(256) void init_hist_kernel(
    const float* __restrict__ W,
    const int* __restrict__ chosen,
    unsigned short* __restrict__ Wb2,
    int* __restrict__ hist)
{
    int blk = blockIdx.x;
    int tid = threadIdx.x;
    if (blk < 1024) {
        int e = (blk * 256 + tid) * 4;
        int g = e >> 17;
        int rem = e & ((MAXGS * DMODEL) - 1);
        int c = rem >> 11;
        int k = rem & (DMODEL - 1);
        int kk = k >> 5, j = k & 31;
        float4 w = *reinterpret_cast<const float4*>(W + e);
        ushort4 o;
        o.x = (unsigned short)bf(w.x); o.y = (unsigned short)bf(w.y);
        o.z = (unsigned short)bf(w.z); o.w = (unsigned short)bf(w.w);
        size_t dst = (((size_t)g * NKK + kk) * MAXGS + c) * 32 + j;
        *reinterpret_cast<ushort4*>(Wb2 + dst) = o;
    } else {
        int hb = blk - 1024;               // 0..31
        __shared__ int h[NGRP];
        if (tid < NGRP) h[tid] = 0;
        __syncthreads();
        int g = chosen[hb * 256 + tid];
        atomicAdd(&h[g], 1);               // LDS atomic
        __syncthreads();
        if (tid < NGRP) hist[hb * NGRP + tid] = h[tid];
    }
}

// Phase 1 (scan FUSED into scatter): each block loads all 32x8 histograms,
// computes its own group bases locally; block 0 also writes cnt. Then the
// deterministic ascending-b ballot-rank scatter. Saves one launch (~2us).
__global__ __launch_bounds__(256) void scatter_kernel(const int* __restrict__ chosen,
                                                      const int* __restrict__ hist,
                                                      int* __restrict__ lists,
                                                      int* __restrict__ cnt) {
    __shared__ int hloc[NBLK * NGRP];
    __shared__ int gbase[NGRP];
    __shared__ int wcnt[4][NGRP];
    __shared__ int wbase[4][NGRP];
    int tid  = threadIdx.x;
    int blk  = blockIdx.x;
    int w    = tid >> 6;
    int lane = tid & 63;

    if (tid < NBLK * NGRP) hloc[tid] = hist[tid];
    __syncthreads();
    if (tid < NGRP) {
        int s = 0;
        for (int b2 = 0; b2 < blk; ++b2) s += hloc[b2 * NGRP + tid];
        gbase[tid] = s;
        if (blk == 0) {
            int tot = 0;
            for (int b2 = 0; b2 < NBLK; ++b2) tot += hloc[b2 * NGRP + tid];
            cnt[tid * CNT_STRIDE] = tot;
        }
    }

    int b = blk * 256 + tid;
    int g = chosen[b];
    int rank = 0;
    unsigned long long below = (1ull << lane) - 1ull;
    #pragma unroll
    for (int gg = 0; gg < NGRP; ++gg) {
        unsigned long long m = __ballot(g == gg);
        if (g == gg) rank = __popcll(m & below);
        if (lane == gg) wcnt[w][gg] = __popcll(m);
    }
    __syncthreads();
    if (tid < NGRP) {
        int base = gbase[tid];
        #pragma unroll
        for (int ww = 0; ww < 4; ++ww) {
            wbase[ww][tid] = base;
            base += wcnt[ww][tid];
        }
    }
    __syncthreads();
    lists[g * BATCH + wbase[w][g] + rank] = b;
}

// Phase 2: GEMM with half-K T14 pipeline.
// r15 proved stage(11us, HBM) + compute(~6us, L2) fixed both walls but runs
// them SERIAL per block. Here: stage K-half0 -> raw s_barrier (NO vmcnt
// drain) -> issue half1 A-loads (pinned by sched_barrier so they can't sink)
// -> compute half0 (B-waits retire streaming A-loads early: harmless) ->
// vmcnt(0) + ds_write half1 -> barrier -> compute half1. HBM latency of
// half1 hides under half0's L2+MFMA work. Swizzle unchanged
// (byte ^= ((r&7)<<4)|((r&1)<<6); XOR touches bits 4-6 only, stays in-half).
__global__ __launch_bounds__(256, 2) void gemm_kernel(
    const float* __restrict__ hidden,
    const float* __restrict__ bias,
    const int* __restrict__ gsizes,
    const int* __restrict__ cnt,
    const int* __restrict__ lists,
    const unsigned short* __restrict__ Wb2,
    float* __restrict__ out)
{
    int bid = blockIdx.x;
    int g = bid & (NGRP - 1);      // group <-> XCD alignment: Wb2[g] L2-resident
    int t = bid >> 3;
    int c = cnt[g * CNT_STRIDE];
    int m0 = t * TM;
    if (m0 >= c) return;           // uniform dead-block exit

    __shared__ unsigned short A[TM][DMODEL];   // bf16, 64 KB

    int tid  = threadIdx.x;
    int w    = tid >> 6;           // wave 0..3
    int lane = tid & 63;
    int lrow = lane & 15;
    int kg   = lane >> 4;          // 0..3

    const float* src[4];
    #pragma unroll
    for (int i = 0; i < 4; ++i) {
        int m  = m0 + 4 * w + i;
        int ms = m < c ? m : c - 1;          // tail: dup last row (guarded)
        src[i] = hidden + ((size_t)lists[g * BATCH + ms] * NGRP + g) * DMODEL
               + lane * 4;
    }

    // ---- stage half 0 (k 0..1023): 4KB burst per row, 2-row pipeline ----
    {
        f32x4 ra[4], rb[4];
        #pragma unroll
        for (int h = 0; h < 4; ++h)
            ra[h] = *reinterpret_cast<const f32x4*>(src[0] + h * 256);
        #pragma unroll
        for (int h = 0; h < 4; ++h)
            rb[h] = *reinterpret_cast<const f32x4*>(src[1] + h * 256);
        #pragma unroll
        for (int i = 0; i < 4; ++i) {
            int r = 4 * w + i;
            int swz = ((r & 7) << 4) | ((r & 1) << 6);
            char* abase = (char*)&A[r][0];
            #pragma unroll
            for (int h = 0; h < 4; ++h) {
                f32x4 v = ra[h];
                short4v o;
                o[0] = bf(v[0]); o[1] = bf(v[1]); o[2] = bf(v[2]); o[3] = bf(v[3]);
                int byte = (h * 512 + lane * 8) ^ swz;
                *reinterpret_cast<short4v*>(abase + byte) = o;
            }
            if (i < 3) {
                #pragma unroll
                for (int h = 0; h < 4; ++h) ra[h] = rb[h];
                if (i < 2) {
                    #pragma unroll
                    for (int h = 0; h < 4; ++h)
                        rb[h] = *reinterpret_cast<const f32x4*>(src[i + 2] + h * 256);
                }
            }
        }
    }

    // ---- issue half-1 A-loads NOW (overlap with compute half 0) ----
    f32x4 rc[16];
    #pragma unroll
    for (int i = 0; i < 4; ++i)
        #pragma unroll
        for (int h = 0; h < 4; ++h)
            rc[i * 4 + h] = *reinterpret_cast<const f32x4*>(src[i] + 1024 + h * 256);
    __builtin_amdgcn_sched_barrier(0);       // pin: loads can't sink below

    // barrier WITHOUT vmcnt drain (syncthreads would wait on rc!)
    asm volatile("s_waitcnt lgkmcnt(0)" ::: "memory");
    __builtin_amdgcn_s_barrier();
    __builtin_amdgcn_sched_barrier(0);

    int swzr = ((lrow & 7) << 4) | ((lrow & 1) << 6);
    const char* arow = (const char*)&A[lrow][0];
    const unsigned short* bp =
        Wb2 + (size_t)g * NKK * MAXGS * 32 + (w * 16 + lrow) * 32 + kg * 8;

    f32x4 acc = f32x4{0, 0, 0, 0};

    // ---- compute half 0: kk 0..31 ----
    #pragma unroll 8
    for (int kk = 0; kk < NKK / 2; ++kk) {
        int byte = (kk * 64 + kg * 16) ^ swzr;
        short8 af  = *reinterpret_cast<const short8*>(arow + byte);
        short8 bfr = *reinterpret_cast<const short8*>(bp + (size_t)kk * MAXGS * 32);
        acc = __builtin_amdgcn_mfma_f32_16x16x32_bf16(af, bfr, acc, 0, 0, 0);
    }

    // ---- land half 1: wait loads, convert, write ----
    asm volatile("s_waitcnt vmcnt(0)" ::: "memory");
    #pragma unroll
    for (int i = 0; i < 4; ++i) {
        int r = 4 * w + i;
        int swz = ((r & 7) << 4) | ((r & 1) << 6);
        char* abase = (char*)&A[r][0];
        #pragma unroll
        for (int h = 0; h < 4; ++h) {
            f32x4 v = rc[i * 4 + h];
            short4v o;
            o[0] = bf(v[0]); o[1] = bf(v[1]); o[2] = bf(v[2]); o[3] = bf(v[3]);
            int byte = (2048 + h * 512 + lane * 8) ^ swz;
            *reinterpret_cast<short4v*>(abase + byte) = o;
        }
    }
    asm volatile("s_waitcnt lgkmcnt(0)" ::: "memory");
    __builtin_amdgcn_s_barrier();
    __builtin_amdgcn_sched_barrier(0);

    // ---- compute half 1: kk 32..63 ----
    #pragma unroll 8
    for (int kk = NKK / 2; kk < NKK; ++kk) {
        int byte = (kk * 64 + kg * 16) ^ swzr;
        short8 af  = *reinterpret_cast<const short8*>(arow + byte);
        short8 bfr = *reinterpret_cast<const short8*>(bp + (size_t)kk * MAXGS * 32);
        acc = __builtin_amdgcn_mfma_f32_16x16x32_bf16(af, bfr, acc, 0, 0, 0);
    }

    // epilogue: C col = lrow (n within group), row = kg*4 + r
    int gsz = gsizes[g];
    int n = w * 16 + lrow;
    float bv = bias[g * MAXGS + n];
    #pragma unroll
    for (int r = 0; r < 4; ++r) {
        int m = m0 + kg * 4 + r;
        if (m < c) {
            int s = lists[g * BATCH + m];
            out[(size_t)s * MAXGS + n] = acc[r] + bv;   // padded n: 0+0 == 0
            out[(size_t)(BATCH + s) * MAXGS + n] = (n < gsz) ? 1.0f : 0.0f;
        }
    }
}

extern "C" void kernel_launch(void* const* d_in, const int* in_sizes, int n_in,
                              void* d_out, int out_size, void* d_ws, size_t ws_size,
                              hipStream_t stream) {
    const float* hidden = (const float*)d_in[0];   // [8192, 8, 2048] f32
    const int*   chosen = (const int*)d_in[1];     // [8192] i32
    const float* W      = (const float*)d_in[2];   // [8, 64, 2048] f32 (zero-padded)
    const float* bias   = (const float*)d_in[3];   // [8, 64] f32 (zero-padded)
    const int*   gs     = (const int*)d_in[4];     // [8] i32
    float* out = (float*)d_out;                    // [8192*64 preds | 8192*64 valid]

    char* ws = (char*)d_ws;
    int* cnt   = (int*)(ws + CNT_OFF);
    int* hist  = (int*)(ws + HIST_OFF);
    int* lists = (int*)(ws + LISTS_OFF);
    unsigned short* Wb2 = (unsigned short*)(ws + W_OFF);

    init_hist_kernel<<<dim3(1024 + NBLK), dim3(256), 0, stream>>>(W, chosen, Wb2, hist);
    scatter_kernel<<<dim3(NBLK), dim3(256), 0, stream>>>(chosen, hist, lists, cnt);
    gemm_kernel<<<dim3(NGRP * TILES), dim3(256), 0, stream>>>(
        hidden, bias, gs, cnt, lists, Wb2, out);
}

// Round 17
// 35.856 us; speedup vs baseline: 1.4079x; 1.0089x over previous
//
#include <hip/hip_runtime.h>
#include <hip/hip_bf16.h>

// Problem constants
#define BATCH   8192
#define NGRP    8
#define MAXGS   64
#define DMODEL  2048
#define TM      16
#define TILES   (BATCH / TM)      // 512
#define NBLK    32                // histogram/scatter blocks
#define NKK     (DMODEL / 32)     // 64 K-chunks total
#define KC      512               // f32 per phase per row
#define NPH     (DMODEL / KC)     // 4 phases
#define KKP     (KC / 32)         // 16 kk per phase

typedef __attribute__((ext_vector_type(8))) short  short8;
typedef __attribute__((ext_vector_type(4))) float  f32x4;

// ws layout
#define CNT_OFF   0                        // int cnt[8*16] (64B-padded)
#define HIST_OFF  512                      // int hist[32][8]
#define LISTS_OFF 4096                     // int lists[8][8192]
#define W_OFF     (LISTS_OFF + NGRP * BATCH * 4)
#define CNT_STRIDE 16

static __device__ __forceinline__ short bf(float f) {
    __hip_bfloat16 h = __float2bfloat16(f);
    return (short)__bfloat16_as_ushort(h);
}

// Phase 0 (fused): blocks < 1024 repack W (f32 [g][c][k] -> bf16 Wb2
// [g][kk][c][j]): per-MFMA B-load = 1KB contiguous (Wall-B fix, r15-proven).
// Blocks >= 1024: per-block group histogram of `chosen` (LDS atomics).
__global__ __launch_bounds__(256) void init_hist_kernel(
    const float* __restrict__ W,
    const int* __restrict__ chosen,
    unsigned short* __restrict__ Wb2,
    int* __restrict__ hist)
{
    int blk = blockIdx.x;
    int tid = threadIdx.x;
    if (blk < 1024) {
        int e = (blk * 256 + tid) * 4;
        int g = e >> 17;
        int rem = e & ((MAXGS * DMODEL) - 1);
        int c = rem >> 11;
        int k = rem & (DMODEL - 1);
        int kk = k >> 5, j = k & 31;
        float4 w = *reinterpret_cast<const float4*>(W + e);
        ushort4 o;
        o.x = (unsigned short)bf(w.x); o.y = (unsigned short)bf(w.y);
        o.z = (unsigned short)bf(w.z); o.w = (unsigned short)bf(w.w);
        size_t dst = (((size_t)g * NKK + kk) * MAXGS + c) * 32 + j;
        *reinterpret_cast<ushort4*>(Wb2 + dst) = o;
    } else {
        int hb = blk - 1024;               // 0..31
        __shared__ int h[NGRP];
        if (tid < NGRP) h[tid] = 0;
        __syncthreads();
        int g = chosen[hb * 256 + tid];
        atomicAdd(&h[g], 1);               // LDS atomic
        __syncthreads();
        if (tid < NGRP) hist[hb * NGRP + tid] = h[tid];
    }
}

// Phase 1: scan fused into scatter; deterministic ascending-b ballot ranks.
__global__ __launch_bounds__(256) void scatter_kernel(const int* __restrict__ chosen,
                                                      const int* __restrict__ hist,
                                                      int* __restrict__ lists,
                                                      int* __restrict__ cnt) {
    __shared__ int hloc[NBLK * NGRP];
    __shared__ int gbase[NGRP];
    __shared__ int wcnt[4][NGRP];
    __shared__ int wbase[4][NGRP];
    int tid  = threadIdx.x;
    int blk  = blockIdx.x;
    int w    = tid >> 6;
    int lane = tid & 63;

    if (tid < NBLK * NGRP) hloc[tid] = hist[tid];
    __syncthreads();
    if (tid < NGRP) {
        int s = 0;
        for (int b2 = 0; b2 < blk; ++b2) s += hloc[b2 * NGRP + tid];
        gbase[tid] = s;
        if (blk == 0) {
            int tot = 0;
            for (int b2 = 0; b2 < NBLK; ++b2) tot += hloc[b2 * NGRP + tid];
            cnt[tid * CNT_STRIDE] = tot;
        }
    }

    int b = blk * 256 + tid;
    int g = chosen[b];
    int rank = 0;
    unsigned long long below = (1ull << lane) - 1ull;
    #pragma unroll
    for (int gg = 0; gg < NGRP; ++gg) {
        unsigned long long m = __ballot(g == gg);
        if (g == gg) rank = __popcll(m & below);
        if (lane == gg) wcnt[w][gg] = __popcll(m);
    }
    __syncthreads();
    if (tid < NGRP) {
        int base = gbase[tid];
        #pragma unroll
        for (int ww = 0; ww < 4; ++ww) {
            wbase[ww][tid] = base;
            base += wcnt[ww][tid];
        }
    }
    __syncthreads();
    lists[g * BATCH + wbase[w][g] + rank] = b;
}

#define LGKM0_BAR()                                          \
    asm volatile("s_waitcnt lgkmcnt(0)" ::: "memory");       \
    __builtin_amdgcn_s_barrier();                            \
    __builtin_amdgcn_sched_barrier(0)

// Phase 2: PRODUCER/CONSUMER gemm.
// WHY (r16 post-mortem): within ONE wave, vmcnt retires in order, so any
// B-wait forces all earlier-issued A-loads to retire -- single-wave overlap
// is structurally impossible (r7/r16 both died on this). Separate waves have
// SEPARATE vmcnt queues. r8's producer/consumer failed only because its
// consumers sat on Wall-B (4KB-stride B = 22us); with coalesced Wb2 the
// consumer phase is ~6us, so the split now pays.
//   waves 0-3 = producers: burst-load A rows (f32, 2KB/row/phase,
//     back-to-back), cvt->bf16, swizzled ds_write. Queue = A only.
//   waves 4-7 = consumers: n-split 16 cols, ds_read A + coalesced-B + MFMA.
//     Queue = L2 B-loads only.
// Double-buffered KC=512 phases (2 x [16][512] bf16 = 32KB), 5 matched
// barriers each side, disjoint buffers per phase window.
__global__ __launch_bounds__(512, 2) void gemm_kernel(
    const float* __restrict__ hidden,
    const float* __restrict__ bias,
    const int* __restrict__ gsizes,
    const int* __restrict__ cnt,
    const int* __restrict__ lists,
    const unsigned short* __restrict__ Wb2,
    float* __restrict__ out)
{
    int bid = blockIdx.x;
    int g = bid & (NGRP - 1);      // group <-> XCD alignment: Wb2[g] L2-resident
    int t = bid >> 3;
    int c = cnt[g * CNT_STRIDE];
    int m0 = t * TM;
    if (m0 >= c) return;           // uniform dead-block exit (before barriers)

    __shared__ unsigned short A[2][TM][KC];   // 32 KB

    int tid  = threadIdx.x;
    int w    = tid >> 6;           // 0..7
    int lane = tid & 63;

    if (w < 4) {
        // ---------------- PRODUCER: rows 4w..4w+3 ----------------
        const float* src[4];
        #pragma unroll
        for (int i = 0; i < 4; ++i) {
            int m  = m0 + 4 * w + i;
            int ms = m < c ? m : c - 1;      // tail: dup last row (guarded)
            src[i] = hidden + ((size_t)lists[g * BATCH + ms] * NGRP + g) * DMODEL
                   + lane * 8;               // 8 f32 per lane per row-phase
        }
        #define PRODUCE(buf, ph)                                               \
            {                                                                  \
                f32x4 v0[4], v1[4];                                            \
                _Pragma("unroll")                                              \
                for (int i = 0; i < 4; ++i) {                                  \
                    v0[i] = *reinterpret_cast<const f32x4*>(src[i] + (ph) * KC);     \
                    v1[i] = *reinterpret_cast<const f32x4*>(src[i] + (ph) * KC + 4); \
                }                                                              \
                _Pragma("unroll")                                              \
                for (int i = 0; i < 4; ++i) {                                  \
                    int r = 4 * w + i;                                         \
                    int swz = ((r & 7) << 4) | ((r & 1) << 6);                 \
                    short8 o;                                                  \
                    o[0] = bf(v0[i][0]); o[1] = bf(v0[i][1]);                  \
                    o[2] = bf(v0[i][2]); o[3] = bf(v0[i][3]);                  \
                    o[4] = bf(v1[i][0]); o[5] = bf(v1[i][1]);                  \
                    o[6] = bf(v1[i][2]); o[7] = bf(v1[i][3]);                  \
                    char* ab = (char*)&A[buf][r][0];                           \
                    *reinterpret_cast<short8*>(ab + ((lane * 16) ^ swz)) = o;  \
                }                                                              \
            }
        PRODUCE(0, 0)
        LGKM0_BAR();                         // buf0 ready
        #pragma unroll
        for (int ch = 0; ch < NPH; ++ch) {
            if (ch + 1 < NPH) PRODUCE((ch + 1) & 1, ch + 1)
            LGKM0_BAR();                     // phase window closes
        }
        #undef PRODUCE
    } else {
        // ---------------- CONSUMER: cols [16cw, 16cw+16) ----------------
        int cw   = w - 4;
        int lrow = lane & 15;
        int kg   = lane >> 4;
        int swzr = ((lrow & 7) << 4) | ((lrow & 1) << 6);
        const unsigned short* bp =
            Wb2 + (size_t)g * NKK * MAXGS * 32 + (cw * 16 + lrow) * 32 + kg * 8;

        f32x4 acc = f32x4{0, 0, 0, 0};
        LGKM0_BAR();                         // wait buf0
        #pragma unroll
        for (int ch = 0; ch < NPH; ++ch) {
            const char* arow = (const char*)&A[ch & 1][lrow][0];
            #pragma unroll
            for (int k2 = 0; k2 < KKP; ++k2) {
                int byte = (k2 * 64 + kg * 16) ^ swzr;
                short8 af  = *reinterpret_cast<const short8*>(arow + byte);
                short8 bfr = *reinterpret_cast<const short8*>(
                    bp + (size_t)(ch * KKP + k2) * MAXGS * 32);
                acc = __builtin_amdgcn_mfma_f32_16x16x32_bf16(af, bfr, acc, 0, 0, 0);
            }
            LGKM0_BAR();                     // done with this buffer
        }

        // epilogue: C col = lrow (n), row = kg*4 + r
        int gsz = gsizes[g];
        int n = cw * 16 + lrow;
        float bv = bias[g * MAXGS + n];
        #pragma unroll
        for (int r = 0; r < 4; ++r) {
            int m = m0 + kg * 4 + r;
            if (m < c) {
                int s = lists[g * BATCH + m];
                out[(size_t)s * MAXGS + n] = acc[r] + bv;   // padded n: 0+0 == 0
                out[(size_t)(BATCH + s) * MAXGS + n] = (n < gsz) ? 1.0f : 0.0f;
            }
        }
    }
}

extern "C" void kernel_launch(void* const* d_in, const int* in_sizes, int n_in,
                              void* d_out, int out_size, void* d_ws, size_t ws_size,
                              hipStream_t stream) {
    const float* hidden = (const float*)d_in[0];   // [8192, 8, 2048] f32
    const int*   chosen = (const int*)d_in[1];     // [8192] i32
    const float* W      = (const float*)d_in[2];   // [8, 64, 2048] f32 (zero-padded)
    const float* bias   = (const float*)d_in[3];   // [8, 64] f32 (zero-padded)
    const int*   gs     = (const int*)d_in[4];     // [8] i32
    float* out = (float*)d_out;                    // [8192*64 preds | 8192*64 valid]

    char* ws = (char*)d_ws;
    int* cnt   = (int*)(ws + CNT_OFF);
    int* hist  = (int*)(ws + HIST_OFF);
    int* lists = (int*)(ws + LISTS_OFF);
    unsigned short* Wb2 = (unsigned short*)(ws + W_OFF);

    init_hist_kernel<<<dim3(1024 + NBLK), dim3(256), 0, stream>>>(W, chosen, Wb2, hist);
    scatter_kernel<<<dim3(NBLK), dim3(256), 0, stream>>>(chosen, hist, lists, cnt);
    gemm_kernel<<<dim3(NGRP * TILES), dim3(512), 0, stream>>>(
        hidden, bias, gs, cnt, lists, Wb2, out);
}